// Round 2
// baseline (166.464 us; speedup 1.0000x reference)
//
#include <hip/hip_runtime.h>

// Per-row 2D Euclidean distance, summed, divided by (B+1).
// pred/target: [B,2] float32 row-major. Output: 1 float.
// n4 = B*2/4 = 4,194,304 float4 per input.
//
// Lessons:
//  R2: same-address float atomics serialize (+100us) -> never accumulate via atomics.
//  R1==R4==R5: access shape (serial/flat/block-contiguous) doesn't move the
//    partial kernel -> memory-system plateau ~5.6 TB/s effective (half L3 hits).
//  R6: 2048 blocks + unroll-1 sequential batches halves per-wave MLP -> +2us.
//    OccupancyPercent is not tracking a real limiter; churn theory dead.
// This round: R0's proven partial structure (4096 one-shot blocks, 8 dwordx4
// fully in flight) + FUSED final reduction via last-block-done protocol to
// remove the ~3us second-dispatch tail. Contention de-risked with two-level
// counters: 64 spread sub-counters (one u32 atomicAdd per block, 64 blocks
// each) -> 1 master (64 RMWs total). Counters zeroed by a 272 B in-graph
// hipMemsetAsync (d_ws is re-poisoned between runs; self-reset unsafe).

#define NBLOCKS 4096
#define NTHREADS 256
#define VPT 4                       // float4 per thread per array
#define SUBGROUPS 64                // spread sub-counters
#define BLK_PER_SUB (NBLOCKS / SUBGROUPS)  // 64

__global__ __launch_bounds__(NTHREADS) void dist_fused(
    const float4* __restrict__ pred,
    const float4* __restrict__ targ,
    float* __restrict__ partials,        // NBLOCKS floats
    unsigned int* __restrict__ counters, // [SUBGROUPS] sub + [SUBGROUPS] master
    float* __restrict__ out,
    int n4, float inv_np1) {
    const int base = blockIdx.x * (NTHREADS * VPT) + threadIdx.x;
    float s = 0.0f;

    if (base + 3 * NTHREADS < n4) {
        float4 p0 = pred[base];
        float4 p1 = pred[base + NTHREADS];
        float4 p2 = pred[base + 2 * NTHREADS];
        float4 p3 = pred[base + 3 * NTHREADS];
        float4 t0 = targ[base];
        float4 t1 = targ[base + NTHREADS];
        float4 t2 = targ[base + 2 * NTHREADS];
        float4 t3 = targ[base + 3 * NTHREADS];
        float dx, dy;
        dx = p0.x - t0.x; dy = p0.y - t0.y; s += sqrtf(dx * dx + dy * dy);
        dx = p0.z - t0.z; dy = p0.w - t0.w; s += sqrtf(dx * dx + dy * dy);
        dx = p1.x - t1.x; dy = p1.y - t1.y; s += sqrtf(dx * dx + dy * dy);
        dx = p1.z - t1.z; dy = p1.w - t1.w; s += sqrtf(dx * dx + dy * dy);
        dx = p2.x - t2.x; dy = p2.y - t2.y; s += sqrtf(dx * dx + dy * dy);
        dx = p2.z - t2.z; dy = p2.w - t2.w; s += sqrtf(dx * dx + dy * dy);
        dx = p3.x - t3.x; dy = p3.y - t3.y; s += sqrtf(dx * dx + dy * dy);
        dx = p3.z - t3.z; dy = p3.w - t3.w; s += sqrtf(dx * dx + dy * dy);
    } else {
        // Generic tail (unused at this exact shape).
        #pragma unroll
        for (int k = 0; k < VPT; ++k) {
            int j = base + k * NTHREADS;
            if (j < n4) {
                float4 p = pred[j];
                float4 t = targ[j];
                float dx0 = p.x - t.x, dy0 = p.y - t.y;
                float dx1 = p.z - t.z, dy1 = p.w - t.w;
                s += sqrtf(dx0 * dx0 + dy0 * dy0) + sqrtf(dx1 * dx1 + dy1 * dy1);
            }
        }
    }

    // Wave-64 reduction, then cross-wave via LDS.
    #pragma unroll
    for (int off = 32; off > 0; off >>= 1)
        s += __shfl_down(s, off, 64);
    __shared__ float smem[NTHREADS / 64];
    __shared__ int isLast;
    int lane = threadIdx.x & 63;
    int wave = threadIdx.x >> 6;
    if (lane == 0) smem[wave] = s;
    __syncthreads();

    if (threadIdx.x == 0) {
        float bsum = 0.0f;
        #pragma unroll
        for (int w = 0; w < NTHREADS / 64; ++w) bsum += smem[w];
        // Publish partial, then announce completion. Release on the RMW orders
        // the partial store before the counter becomes visible; acq_rel chains
        // transitively sub -> master -> last block's reads.
        __hip_atomic_store(&partials[blockIdx.x], bsum, __ATOMIC_RELAXED,
                           __HIP_MEMORY_SCOPE_AGENT);
        int last = 0;
        unsigned int sub = blockIdx.x / BLK_PER_SUB;  // 64 blocks per subcounter
        unsigned int prev = __hip_atomic_fetch_add(&counters[sub], 1u,
                                                   __ATOMIC_ACQ_REL,
                                                   __HIP_MEMORY_SCOPE_AGENT);
        if (prev == BLK_PER_SUB - 1) {
            unsigned int prevM = __hip_atomic_fetch_add(&counters[SUBGROUPS], 1u,
                                                        __ATOMIC_ACQ_REL,
                                                        __HIP_MEMORY_SCOPE_AGENT);
            last = (prevM == SUBGROUPS - 1);
        }
        isLast = last;
    }
    __syncthreads();

    if (isLast) {
        // Last block: reduce all NBLOCKS partials (16 KB, mostly L2-resident).
        const float4* p4 = (const float4*)partials;
        float acc = 0.0f;
        #pragma unroll
        for (int i = 0; i < NBLOCKS / 4 / NTHREADS; ++i) {
            float4 v = p4[i * NTHREADS + threadIdx.x];
            acc += (v.x + v.y) + (v.z + v.w);
        }
        #pragma unroll
        for (int off = 32; off > 0; off >>= 1)
            acc += __shfl_down(acc, off, 64);
        if (lane == 0) smem[wave] = acc;
        __syncthreads();
        if (threadIdx.x == 0) {
            float sv = 0.0f;
            #pragma unroll
            for (int w = 0; w < NTHREADS / 64; ++w) sv += smem[w];
            out[0] = sv * inv_np1;
        }
    }
}

extern "C" void kernel_launch(void* const* d_in, const int* in_sizes, int n_in,
                              void* d_out, int out_size, void* d_ws, size_t ws_size,
                              hipStream_t stream) {
    const float4* pred = (const float4*)d_in[0];
    const float4* targ = (const float4*)d_in[1];
    float* out = (float*)d_out;
    float* partials = (float*)d_ws;
    unsigned int* counters =
        (unsigned int*)((char*)d_ws + NBLOCKS * sizeof(float));

    long long total_floats = (long long)in_sizes[0];  // B*2
    long long n_rows = total_floats / 2;              // B
    int n4 = (int)(total_floats / 4);                 // float4 count

    float inv_np1 = 1.0f / (float)(n_rows + 1);

    // Zero sub-counters + master each launch (graph-capturable async op;
    // required because d_ws is re-poisoned between iterations).
    hipMemsetAsync(counters, 0, (SUBGROUPS + 1) * sizeof(unsigned int), stream);

    dist_fused<<<NBLOCKS, NTHREADS, 0, stream>>>(pred, targ, partials, counters,
                                                 out, n4, inv_np1);
}

// Round 3
// 55.129 us; speedup vs baseline: 3.0196x; 3.0196x over previous
//
#include <hip/hip_runtime.h>

// Per-row 2D Euclidean distance, summed, divided by (B+1).
// pred/target: [B,2] float32 row-major. Output: 1 float.
// n4 = B*2/4 = 4,194,304 float4 per input.
//
// Lessons:
//  R2(old session): same-address ordered atomics serialize (+100us).
//  R1==R4==R5: access shape doesn't move the partial kernel -> memory plateau
//    ~5.6 TB/s effective (half the fetch L3-absorbed).
//  R6: sequential batches halve per-wave MLP -> +2us. Churn theory dead.
//  R7 (last round): acq_rel AGENT atomics on gfx950 = whole-L2
//    writeback/invalidate per op (per-XCD L2s non-coherent) -> 4096 of them
//    collapsed HBM to 280 GB/s, 240us. NEVER use ordered agent atomics per
//    block. Correct cheap protocol: RELAXED agent atomics for all cross-block
//    data (per-access cache-bypass flags, no cache-maintenance ops) +
//    explicit s_waitcnt vmcnt(0) before signaling + RMW return-value deps.
// This round: R0's proven partial (4096 one-shot blocks, 8 dwordx4 in
// flight) + fused last-block-done reduce using the relaxed protocol.

#define NBLOCKS 4096
#define NTHREADS 256
#define VPT 4                                // float4 per thread per array
#define SUBGROUPS 64                         // spread sub-counters
#define BLK_PER_SUB (NBLOCKS / SUBGROUPS)    // 64

__global__ __launch_bounds__(NTHREADS) void dist_fused(
    const float4* __restrict__ pred,
    const float4* __restrict__ targ,
    float* __restrict__ partials,        // NBLOCKS floats
    unsigned int* __restrict__ counters, // [SUBGROUPS] sub + 1 master
    float* __restrict__ out,
    int n4, float inv_np1) {
    const int base = blockIdx.x * (NTHREADS * VPT) + threadIdx.x;
    float s = 0.0f;

    if (base + 3 * NTHREADS < n4) {
        float4 p0 = pred[base];
        float4 p1 = pred[base + NTHREADS];
        float4 p2 = pred[base + 2 * NTHREADS];
        float4 p3 = pred[base + 3 * NTHREADS];
        float4 t0 = targ[base];
        float4 t1 = targ[base + NTHREADS];
        float4 t2 = targ[base + 2 * NTHREADS];
        float4 t3 = targ[base + 3 * NTHREADS];
        float dx, dy;
        dx = p0.x - t0.x; dy = p0.y - t0.y; s += sqrtf(dx * dx + dy * dy);
        dx = p0.z - t0.z; dy = p0.w - t0.w; s += sqrtf(dx * dx + dy * dy);
        dx = p1.x - t1.x; dy = p1.y - t1.y; s += sqrtf(dx * dx + dy * dy);
        dx = p1.z - t1.z; dy = p1.w - t1.w; s += sqrtf(dx * dx + dy * dy);
        dx = p2.x - t2.x; dy = p2.y - t2.y; s += sqrtf(dx * dx + dy * dy);
        dx = p2.z - t2.z; dy = p2.w - t2.w; s += sqrtf(dx * dx + dy * dy);
        dx = p3.x - t3.x; dy = p3.y - t3.y; s += sqrtf(dx * dx + dy * dy);
        dx = p3.z - t3.z; dy = p3.w - t3.w; s += sqrtf(dx * dx + dy * dy);
    } else {
        // Generic tail (unused at this exact shape).
        #pragma unroll
        for (int k = 0; k < VPT; ++k) {
            int j = base + k * NTHREADS;
            if (j < n4) {
                float4 p = pred[j];
                float4 t = targ[j];
                float dx0 = p.x - t.x, dy0 = p.y - t.y;
                float dx1 = p.z - t.z, dy1 = p.w - t.w;
                s += sqrtf(dx0 * dx0 + dy0 * dy0) + sqrtf(dx1 * dx1 + dy1 * dy1);
            }
        }
    }

    // Wave-64 reduction, then cross-wave via LDS.
    #pragma unroll
    for (int off = 32; off > 0; off >>= 1)
        s += __shfl_down(s, off, 64);
    __shared__ float smem[NTHREADS / 64];
    __shared__ int isLast;
    int lane = threadIdx.x & 63;
    int wave = threadIdx.x >> 6;
    if (lane == 0) smem[wave] = s;
    __syncthreads();

    if (threadIdx.x == 0) {
        float bsum = 0.0f;
        #pragma unroll
        for (int w = 0; w < NTHREADS / 64; ++w) bsum += smem[w];
        // RELAXED agent atomic store: per-access cache-bypass (sc flags), no
        // cache-maintenance. Reaches the coherent point; vmcnt(0) confirms.
        __hip_atomic_store(&partials[blockIdx.x], bsum, __ATOMIC_RELAXED,
                           __HIP_MEMORY_SCOPE_AGENT);
        asm volatile("s_waitcnt vmcnt(0)" ::: "memory");
        int last = 0;
        unsigned int sub = blockIdx.x / BLK_PER_SUB;  // 64 blocks/subcounter
        unsigned int prev = __hip_atomic_fetch_add(&counters[sub], 1u,
                                                   __ATOMIC_RELAXED,
                                                   __HIP_MEMORY_SCOPE_AGENT);
        if (prev == BLK_PER_SUB - 1) {
            // Sub RMW returned -> it completed at the coherent point; the
            // master RMW below is therefore ordered after it.
            unsigned int prevM = __hip_atomic_fetch_add(
                &counters[SUBGROUPS], 1u, __ATOMIC_RELAXED,
                __HIP_MEMORY_SCOPE_AGENT);
            last = (prevM == SUBGROUPS - 1);
        }
        isLast = last;
    }
    __syncthreads();

    if (isLast) {
        // Last block: all 4096 partial stores are at the coherent point.
        // Read them with relaxed agent atomic loads (cache-bypass, no
        // buffer_inv). 16 independent loads per thread -> pipelined.
        float acc = 0.0f;
        #pragma unroll
        for (int i = 0; i < NBLOCKS / NTHREADS; ++i) {
            acc += __hip_atomic_load(&partials[i * NTHREADS + threadIdx.x],
                                     __ATOMIC_RELAXED,
                                     __HIP_MEMORY_SCOPE_AGENT);
        }
        #pragma unroll
        for (int off = 32; off > 0; off >>= 1)
            acc += __shfl_down(acc, off, 64);
        if (lane == 0) smem[wave] = acc;
        __syncthreads();
        if (threadIdx.x == 0) {
            float sv = 0.0f;
            #pragma unroll
            for (int w = 0; w < NTHREADS / 64; ++w) sv += smem[w];
            out[0] = sv * inv_np1;
        }
    }
}

extern "C" void kernel_launch(void* const* d_in, const int* in_sizes, int n_in,
                              void* d_out, int out_size, void* d_ws, size_t ws_size,
                              hipStream_t stream) {
    const float4* pred = (const float4*)d_in[0];
    const float4* targ = (const float4*)d_in[1];
    float* out = (float*)d_out;
    float* partials = (float*)d_ws;
    unsigned int* counters =
        (unsigned int*)((char*)d_ws + NBLOCKS * sizeof(float));

    long long total_floats = (long long)in_sizes[0];  // B*2
    long long n_rows = total_floats / 2;              // B
    int n4 = (int)(total_floats / 4);                 // float4 count

    float inv_np1 = 1.0f / (float)(n_rows + 1);

    // Zero counters each launch (graph-capturable async op; d_ws is
    // re-poisoned between iterations so self-reset is unsafe).
    hipMemsetAsync(counters, 0, (SUBGROUPS + 1) * sizeof(unsigned int), stream);

    dist_fused<<<NBLOCKS, NTHREADS, 0, stream>>>(pred, targ, partials, counters,
                                                 out, n4, inv_np1);
}

// Round 4
// 26.840 us; speedup vs baseline: 6.2022x; 2.0540x over previous
//
#include <hip/hip_runtime.h>

// Per-row 2D Euclidean distance, summed, divided by (B+1).
// pred/target: [B,2] float32 row-major. Output: 1 float.
// n4 = B*2/4 = 4,194,304 float4 per input = 4096 blocks * 256 thr * 4.
//
// FINAL STRUCTURE (reverted to best-verified after fusion experiments):
//  R2(old): same-address device atomics serialize (+100us) -> two-kernel.
//  R1==R4==R5: access shape (serial/flat/block-contiguous) doesn't move the
//    partial kernel -> memory-system plateau ~5.6 TB/s effective (half the
//    fetch L3-absorbed; hit fraction set by harness workspace poison-fill).
//  R6: 2048 blocks + unroll-1 sequential batches halves per-wave MLP -> +2us.
//  R7: acq_rel AGENT atomics = per-op L2 writeback/invalidate on gfx950
//    (per-XCD L2s non-coherent) -> 240us. Never ordered agent atomics per block.
//  R8: relaxed protocol fixed that, but 65 counters in 4 cache lines ->
//    4096 RMWs serialize at the LLC (~25us tail, exposed only when the
//    stream is fast). Fusion ledger nets ~0 anyway: saves final dispatch
//    (~3us) but requires in-stream counter-init dispatch (~2-3us, d_ws is
//    re-poisoned between runs) + residual atomic tail. Abandoned.
// Partial kernel: block-contiguous layout, each block owns 16 KB per array;
// thread t loads float4s at {base+t, +256, +512, +768} -> every dwordx4 is a
// unit-stride 4 KB wave segment, 8 independent loads in flight per thread.
// In-graph partial ~24-25us = 86-89% of the 6.3 TB/s achievable read ceiling.

#define NBLOCKS 4096
#define NTHREADS 256
#define VPT 4  // float4 per thread per array

__global__ __launch_bounds__(NTHREADS) void dist_partial(
    const float4* __restrict__ pred,
    const float4* __restrict__ targ,
    float* __restrict__ partials,
    int n4) {
    const int base = blockIdx.x * (NTHREADS * VPT) + threadIdx.x;
    float s = 0.0f;

    if (base + 3 * NTHREADS < n4) {
        float4 p0 = pred[base];
        float4 p1 = pred[base + NTHREADS];
        float4 p2 = pred[base + 2 * NTHREADS];
        float4 p3 = pred[base + 3 * NTHREADS];
        float4 t0 = targ[base];
        float4 t1 = targ[base + NTHREADS];
        float4 t2 = targ[base + 2 * NTHREADS];
        float4 t3 = targ[base + 3 * NTHREADS];
        float dx, dy;
        dx = p0.x - t0.x; dy = p0.y - t0.y; s += sqrtf(dx * dx + dy * dy);
        dx = p0.z - t0.z; dy = p0.w - t0.w; s += sqrtf(dx * dx + dy * dy);
        dx = p1.x - t1.x; dy = p1.y - t1.y; s += sqrtf(dx * dx + dy * dy);
        dx = p1.z - t1.z; dy = p1.w - t1.w; s += sqrtf(dx * dx + dy * dy);
        dx = p2.x - t2.x; dy = p2.y - t2.y; s += sqrtf(dx * dx + dy * dy);
        dx = p2.z - t2.z; dy = p2.w - t2.w; s += sqrtf(dx * dx + dy * dy);
        dx = p3.x - t3.x; dy = p3.y - t3.y; s += sqrtf(dx * dx + dy * dy);
        dx = p3.z - t3.z; dy = p3.w - t3.w; s += sqrtf(dx * dx + dy * dy);
    } else {
        // Generic tail (unused at this exact shape).
        #pragma unroll
        for (int k = 0; k < VPT; ++k) {
            int j = base + k * NTHREADS;
            if (j < n4) {
                float4 p = pred[j];
                float4 t = targ[j];
                float dx0 = p.x - t.x, dy0 = p.y - t.y;
                float dx1 = p.z - t.z, dy1 = p.w - t.w;
                s += sqrtf(dx0 * dx0 + dy0 * dy0) + sqrtf(dx1 * dx1 + dy1 * dy1);
            }
        }
    }

    // Wave-64 reduction.
    #pragma unroll
    for (int off = 32; off > 0; off >>= 1)
        s += __shfl_down(s, off, 64);
    __shared__ float smem[NTHREADS / 64];
    int lane = threadIdx.x & 63;
    int wave = threadIdx.x >> 6;
    if (lane == 0) smem[wave] = s;
    __syncthreads();
    if (threadIdx.x == 0) {
        float bsum = 0.0f;
        #pragma unroll
        for (int w = 0; w < NTHREADS / 64; ++w) bsum += smem[w];
        partials[blockIdx.x] = bsum;
    }
}

__global__ __launch_bounds__(NTHREADS) void dist_final(
    const float4* __restrict__ partials4,   // NBLOCKS floats = NBLOCKS/4 float4
    int n4,
    float* __restrict__ out,
    float inv_np1) {
    float acc = 0.0f;
    for (int i = threadIdx.x; i < n4; i += NTHREADS) {
        float4 v = partials4[i];
        acc += (v.x + v.y) + (v.z + v.w);
    }
    #pragma unroll
    for (int off = 32; off > 0; off >>= 1)
        acc += __shfl_down(acc, off, 64);
    __shared__ float smem[NTHREADS / 64];
    int lane = threadIdx.x & 63;
    int wave = threadIdx.x >> 6;
    if (lane == 0) smem[wave] = acc;
    __syncthreads();
    if (threadIdx.x == 0) {
        float sv = 0.0f;
        #pragma unroll
        for (int w = 0; w < NTHREADS / 64; ++w) sv += smem[w];
        out[0] = sv * inv_np1;
    }
}

extern "C" void kernel_launch(void* const* d_in, const int* in_sizes, int n_in,
                              void* d_out, int out_size, void* d_ws, size_t ws_size,
                              hipStream_t stream) {
    const float4* pred = (const float4*)d_in[0];
    const float4* targ = (const float4*)d_in[1];
    float* out = (float*)d_out;
    float* partials = (float*)d_ws;

    long long total_floats = (long long)in_sizes[0];  // B*2
    long long n_rows = total_floats / 2;              // B
    int n4 = (int)(total_floats / 4);                 // float4 count

    float inv_np1 = 1.0f / (float)(n_rows + 1);

    dist_partial<<<NBLOCKS, NTHREADS, 0, stream>>>(pred, targ, partials, n4);
    dist_final<<<1, NTHREADS, 0, stream>>>((const float4*)partials, NBLOCKS / 4,
                                           out, inv_np1);
}